// Round 3
// baseline (1751.660 us; speedup 1.0000x reference)
//
#include <hip/hip_runtime.h>
#include <stdint.h>

// ---------- types ----------
typedef __attribute__((ext_vector_type(8))) short short8;
typedef __attribute__((ext_vector_type(4))) float floatx4;

__device__ inline float bf2f(unsigned short u) {
  union { unsigned int i; float f; } v; v.i = ((unsigned int)u) << 16; return v.f;
}
__device__ inline unsigned short f2bf(float f) {
  union { float f; unsigned int i; } v; v.f = f;
  unsigned int r = v.i + 0x7FFFu + ((v.i >> 16) & 1u);  // round-nearest-even
  return (unsigned short)(r >> 16);
}

// ---------- small utility kernels ----------
__global__ void zero_f32(float* __restrict__ p, int n) {
  int i = blockIdx.x * blockDim.x + threadIdx.x;
  if (i < n) p[i] = 0.0f;
}

__global__ void count_edges(const int* __restrict__ dst, const int* __restrict__ et,
                            float* __restrict__ cnt, int E, int R) {
  int e = blockIdx.x * blockDim.x + threadIdx.x;
  if (e < E) atomicAdd(&cnt[(size_t)dst[e] * R + et[e]], 1.0f);
}

__global__ void invert_cnt(float* __restrict__ p, int n) {
  int i = blockIdx.x * blockDim.x + threadIdx.x;
  if (i < n) p[i] = 1.0f / fmaxf(p[i], 1.0f);
}

// ---------- transform: Y[n][g*64+c] = sum_d X[n][d] * W_g[d][c]  (g<R, bf16 out)
// ----------            acc[n][c]    = b[c] + sum_d X[n][d] * root[d][c]  (g==R, f32 out)
// Inputs f32; rounded to bf16 for MFMA fragments (f32 accumulate).
// MFMA 16x16x32 bf16. A layout: lane holds A[m=lane&15][k=(lane>>4)*8+j]
// B layout: lane holds B[k=(lane>>4)*8+j][n=lane&15]
// C/D layout: col = lane&15, row = (lane>>4)*4 + reg   [verified m89/m91]
__global__ void __launch_bounds__(256)
transform(const float* __restrict__ X, const float* __restrict__ W,
          const float* __restrict__ root, const float* __restrict__ bias,
          unsigned short* __restrict__ Y, float* __restrict__ acc, int N, int R)
{
  const int g    = blockIdx.y;            // 0..R  (R == root/bias group)
  const int lane = threadIdx.x & 63;
  const int wave = threadIdx.x >> 6;
  const int lc   = lane & 15;
  const int quad = lane >> 4;
  const float* B = (g < R) ? (W + (size_t)g * 64 * 64) : root;

  // load B fragments once per wave (kept in VGPRs across node loop)
  short8 bfrag[2][4];
#pragma unroll
  for (int kc = 0; kc < 2; ++kc)
#pragma unroll
    for (int nt = 0; nt < 4; ++nt) {
      short8 f;
#pragma unroll
      for (int j = 0; j < 8; ++j)
        f[j] = (short)f2bf(B[(size_t)(kc * 32 + quad * 8 + j) * 64 + nt * 16 + lc]);
      bfrag[kc][nt] = f;
    }

  const int tiles  = (N + 15) >> 4;
  const int stride = gridDim.x * 4;
  for (int t = blockIdx.x * 4 + wave; t < tiles; t += stride) {
    const int nb  = t << 4;
    const int row = min(nb + lc, N - 1);           // clamp for tail tile
    const float* xr = X + (size_t)row * 64;
    short8 a0, a1;
#pragma unroll
    for (int j = 0; j < 8; ++j) {
      a0[j] = (short)f2bf(xr[quad * 8 + j]);
      a1[j] = (short)f2bf(xr[32 + quad * 8 + j]);
    }
#pragma unroll
    for (int nt = 0; nt < 4; ++nt) {
      floatx4 d = {0.f, 0.f, 0.f, 0.f};
      d = __builtin_amdgcn_mfma_f32_16x16x32_bf16(a0, bfrag[0][nt], d, 0, 0, 0);
      d = __builtin_amdgcn_mfma_f32_16x16x32_bf16(a1, bfrag[1][nt], d, 0, 0, 0);
      const int c = nt * 16 + lc;
      if (g < R) {
#pragma unroll
        for (int i = 0; i < 4; ++i) {
          int r_ = nb + quad * 4 + i;
          if (r_ < N) Y[(size_t)r_ * (R * 64) + g * 64 + c] = f2bf(d[i]);
        }
      } else {
        float bv = bias[c];
#pragma unroll
        for (int i = 0; i < 4; ++i) {
          int r_ = nb + quad * 4 + i;
          if (r_ < N) acc[(size_t)r_ * 64 + c] = d[i] + bv;
        }
      }
    }
  }
}

// ---------- edge aggregation: acc[dst][k] += Y[src][et*64+k] * inv[dst*R+et]
__global__ void edge_agg(const unsigned short* __restrict__ Y,
                         const int* __restrict__ src, const int* __restrict__ dst,
                         const int* __restrict__ et, const float* __restrict__ inv,
                         float* __restrict__ acc, int E, int R)
{
  const int total = E * 64;   // 102.4M < 2^31
  int t = blockIdx.x * blockDim.x + threadIdx.x;
  const int stride = gridDim.x * blockDim.x;
  for (; t < total; t += stride) {
    int e = t >> 6;
    int k = t & 63;
    int s = src[e], d = dst[e], r = et[e];
    float v = bf2f(Y[(size_t)s * (R * 64) + r * 64 + k]);
    float w = inv[(size_t)d * R + r];
    atomicAdd(&acc[(size_t)d * 64 + k], v * w);
  }
}

__global__ void relu_f32(const float* __restrict__ acc, float* __restrict__ h, int n) {
  int i = blockIdx.x * blockDim.x + threadIdx.x;
  if (i < n) h[i] = fmaxf(acc[i], 0.0f);
}

__global__ void pool_sum(const float* __restrict__ acc, const int* __restrict__ batch,
                         float* __restrict__ gsum, int n) {
  int i = blockIdx.x * blockDim.x + threadIdx.x;
  if (i < n) {
    int node = i >> 6, k = i & 63;
    atomicAdd(&gsum[batch[node] * 64 + k], acc[i]);
  }
}

__global__ void pool_cnt(const int* __restrict__ batch, float* __restrict__ gcnt, int N) {
  int i = blockIdx.x * blockDim.x + threadIdx.x;
  if (i < N) atomicAdd(&gcnt[batch[i]], 1.0f);
}

__global__ void finalize(const float* __restrict__ gsum, const float* __restrict__ gcnt,
                         float* __restrict__ out, int G) {
  int i = blockIdx.x * blockDim.x + threadIdx.x;
  if (i < G * 64) out[i] = gsum[i] / fmaxf(gcnt[i >> 6], 1.0f);
}

// ---------- launch ----------
extern "C" void kernel_launch(void* const* d_in, const int* in_sizes, int n_in,
                              void* d_out, int out_size, void* d_ws, size_t ws_size,
                              hipStream_t stream)
{
  const float* x     = (const float*)d_in[0];
  const int*   ei    = (const int*)d_in[1];
  const int*   etype = (const int*)d_in[2];
  const int*   batch = (const int*)d_in[3];
  const float* W1    = (const float*)d_in[4];
  const float* root1 = (const float*)d_in[5];
  const float* b1    = (const float*)d_in[6];
  const float* W2    = (const float*)d_in[7];
  const float* root2 = (const float*)d_in[8];
  const float* b2    = (const float*)d_in[9];

  const int N = in_sizes[0] / 64;
  const int E = in_sizes[1] / 2;
  const int R = in_sizes[4] / (64 * 64);
  const int G = out_size / 64;
  const int* srcp = ei;
  const int* dstp = ei + E;

  // workspace carve-up (256B aligned): inv | acc | h | Y | gsum+gcnt  (~157 MB)
  char* ws = (char*)d_ws;
  size_t off = 0;
  auto carve = [&](size_t bytes) -> void* {
    void* p = ws + off; off = (off + bytes + 255) & ~(size_t)255; return p;
  };
  float*          inv  = (float*)carve((size_t)N * R * 4);
  float*          acc  = (float*)carve((size_t)N * 64 * 4);
  float*          h    = (float*)carve((size_t)N * 64 * 4);
  unsigned short* Y    = (unsigned short*)carve((size_t)N * R * 64 * 2);
  float*          gsum = (float*)carve(((size_t)G * 64 + G) * 4);
  float*          gcnt = gsum + (size_t)G * 64;
  (void)ws_size; (void)n_in;

  const int nInv = N * R;
  zero_f32<<<(nInv + 255) / 256, 256, 0, stream>>>(inv, nInv);
  zero_f32<<<(G * 64 + G + 255) / 256, 256, 0, stream>>>(gsum, G * 64 + G);

  count_edges<<<(E + 255) / 256, 256, 0, stream>>>(dstp, etype, inv, E, R);
  invert_cnt<<<(nInv + 255) / 256, 256, 0, stream>>>(inv, nInv);

  dim3 tgrid(128, R + 1);
  const int nh = N * 64;
  const int eBlocks = 8192;

  // ---- layer 1 ----
  transform<<<tgrid, 256, 0, stream>>>(x, W1, root1, b1, Y, acc, N, R);
  edge_agg<<<eBlocks, 256, 0, stream>>>(Y, srcp, dstp, etype, inv, acc, E, R);
  relu_f32<<<(nh + 255) / 256, 256, 0, stream>>>(acc, h, nh);

  // ---- layer 2 ----
  transform<<<tgrid, 256, 0, stream>>>(h, W2, root2, b2, Y, acc, N, R);
  edge_agg<<<eBlocks, 256, 0, stream>>>(Y, srcp, dstp, etype, inv, acc, E, R);

  // ---- global mean pool ----
  pool_sum<<<(nh + 255) / 256, 256, 0, stream>>>(acc, batch, gsum, nh);
  pool_cnt<<<(N + 255) / 256, 256, 0, stream>>>(batch, gcnt, N);
  finalize<<<(G * 64 + 255) / 256, 256, 0, stream>>>(gsum, gcnt, (float*)d_out, G);
}

// Round 4
// 1137.217 us; speedup vs baseline: 1.5403x; 1.5403x over previous
//
#include <hip/hip_runtime.h>
#include <stdint.h>

// ---------- types ----------
typedef __attribute__((ext_vector_type(8))) short short8;
typedef __attribute__((ext_vector_type(4))) float floatx4;

__device__ inline float bf2f(unsigned short u) {
  union { unsigned int i; float f; } v; v.i = ((unsigned int)u) << 16; return v.f;
}
__device__ inline unsigned short f2bf(float f) {
  union { float f; unsigned int i; } v; v.f = f;
  unsigned int r = v.i + 0x7FFFu + ((v.i >> 16) & 1u);  // round-nearest-even
  return (unsigned short)(r >> 16);
}

// ---------- small utility kernels ----------
__global__ void zero_f32(float* __restrict__ p, int n) {
  int i = blockIdx.x * blockDim.x + threadIdx.x;
  if (i < n) p[i] = 0.0f;
}

__global__ void count_edges(const int* __restrict__ dst, const int* __restrict__ et,
                            float* __restrict__ cnt, int E, int R) {
  int e = blockIdx.x * blockDim.x + threadIdx.x;
  if (e < E) atomicAdd(&cnt[(size_t)dst[e] * R + et[e]], 1.0f);
}

__global__ void invert_cnt(float* __restrict__ p, int n) {
  int i = blockIdx.x * blockDim.x + threadIdx.x;
  if (i < n) p[i] = 1.0f / fmaxf(p[i], 1.0f);
}

// ---------- transform: Y[n][g*64+c] = sum_d X[n][d] * W_g[d][c]  (g<R, bf16 out)
// ----------            acc[n][c]    = b[c] + sum_d X[n][d] * root[d][c]  (g==R, f32 out)
// Inputs f32; rounded to bf16 for MFMA fragments (f32 accumulate).
// MFMA 16x16x32 bf16. A layout: lane holds A[m=lane&15][k=(lane>>4)*8+j]
// B layout: lane holds B[k=(lane>>4)*8+j][n=lane&15]
// C/D layout: col = lane&15, row = (lane>>4)*4 + reg   [verified m89/m91]
__global__ void __launch_bounds__(256)
transform(const float* __restrict__ X, const float* __restrict__ W,
          const float* __restrict__ root, const float* __restrict__ bias,
          unsigned short* __restrict__ Y, float* __restrict__ acc, int N, int R)
{
  const int g    = blockIdx.y;            // 0..R  (R == root/bias group)
  const int lane = threadIdx.x & 63;
  const int wave = threadIdx.x >> 6;
  const int lc   = lane & 15;
  const int quad = lane >> 4;
  const float* B = (g < R) ? (W + (size_t)g * 64 * 64) : root;

  // load B fragments once per wave (kept in VGPRs across node loop)
  short8 bfrag[2][4];
#pragma unroll
  for (int kc = 0; kc < 2; ++kc)
#pragma unroll
    for (int nt = 0; nt < 4; ++nt) {
      short8 f;
#pragma unroll
      for (int j = 0; j < 8; ++j)
        f[j] = (short)f2bf(B[(size_t)(kc * 32 + quad * 8 + j) * 64 + nt * 16 + lc]);
      bfrag[kc][nt] = f;
    }

  const int tiles  = (N + 15) >> 4;
  const int stride = gridDim.x * 4;
  for (int t = blockIdx.x * 4 + wave; t < tiles; t += stride) {
    const int nb  = t << 4;
    const int row = min(nb + lc, N - 1);           // clamp for tail tile
    const float* xr = X + (size_t)row * 64;
    short8 a0, a1;
#pragma unroll
    for (int j = 0; j < 8; ++j) {
      a0[j] = (short)f2bf(xr[quad * 8 + j]);
      a1[j] = (short)f2bf(xr[32 + quad * 8 + j]);
    }
#pragma unroll
    for (int nt = 0; nt < 4; ++nt) {
      floatx4 d = {0.f, 0.f, 0.f, 0.f};
      d = __builtin_amdgcn_mfma_f32_16x16x32_bf16(a0, bfrag[0][nt], d, 0, 0, 0);
      d = __builtin_amdgcn_mfma_f32_16x16x32_bf16(a1, bfrag[1][nt], d, 0, 0, 0);
      const int c = nt * 16 + lc;
      if (g < R) {
#pragma unroll
        for (int i = 0; i < 4; ++i) {
          int r_ = nb + quad * 4 + i;
          if (r_ < N) Y[(size_t)r_ * (R * 64) + g * 64 + c] = f2bf(d[i]);
        }
      } else {
        float bv = bias[c];
#pragma unroll
        for (int i = 0; i < 4; ++i) {
          int r_ = nb + quad * 4 + i;
          if (r_ < N) acc[(size_t)r_ * 64 + c] = d[i] + bv;
        }
      }
    }
  }
}

// ---------- edge aggregation: acc[dst][k] += Y[src][et*64+k] * inv[dst*R+et]
__global__ void edge_agg(const unsigned short* __restrict__ Y,
                         const int* __restrict__ src, const int* __restrict__ dst,
                         const int* __restrict__ et, const float* __restrict__ inv,
                         float* __restrict__ acc, int E, int R)
{
  const int total = E * 64;   // 102.4M < 2^31
  int t = blockIdx.x * blockDim.x + threadIdx.x;
  const int stride = gridDim.x * blockDim.x;
  for (; t < total; t += stride) {
    int e = t >> 6;
    int k = t & 63;
    int s = src[e], d = dst[e], r = et[e];
    float v = bf2f(Y[(size_t)s * (R * 64) + r * 64 + k]);
    float w = inv[(size_t)d * R + r];
    atomicAdd(&acc[(size_t)d * 64 + k], v * w);
  }
}

__global__ void relu_f32(const float* __restrict__ acc, float* __restrict__ h, int n) {
  int i = blockIdx.x * blockDim.x + threadIdx.x;
  if (i < n) h[i] = fmaxf(acc[i], 0.0f);
}

__global__ void pool_sum(const float* __restrict__ acc, const int* __restrict__ batch,
                         float* __restrict__ gsum, int n) {
  int i = blockIdx.x * blockDim.x + threadIdx.x;
  if (i < n) {
    int node = i >> 6, k = i & 63;
    atomicAdd(&gsum[batch[node] * 64 + k], acc[i]);
  }
}

// batch is sorted (jnp.sort in setup): gcnt[g] = lower_bound(g+1) - lower_bound(g).
// 64 threads, two 17-step binary searches each — replaces the 640us atomic pool_cnt.
__global__ void gcnt_bounds(const int* __restrict__ batch, float* __restrict__ gcnt,
                            int N, int G) {
  int g = blockIdx.x * blockDim.x + threadIdx.x;
  if (g >= G) return;
  int lo0 = 0, hi = N;
  while (lo0 < hi) { int mid = (lo0 + hi) >> 1; if (batch[mid] < g) lo0 = mid + 1; else hi = mid; }
  int lo1 = lo0; hi = N;
  while (lo1 < hi) { int mid = (lo1 + hi) >> 1; if (batch[mid] < g + 1) lo1 = mid + 1; else hi = mid; }
  gcnt[g] = (float)(lo1 - lo0);
}

__global__ void finalize(const float* __restrict__ gsum, const float* __restrict__ gcnt,
                         float* __restrict__ out, int G) {
  int i = blockIdx.x * blockDim.x + threadIdx.x;
  if (i < G * 64) out[i] = gsum[i] / fmaxf(gcnt[i >> 6], 1.0f);
}

// ---------- launch ----------
extern "C" void kernel_launch(void* const* d_in, const int* in_sizes, int n_in,
                              void* d_out, int out_size, void* d_ws, size_t ws_size,
                              hipStream_t stream)
{
  const float* x     = (const float*)d_in[0];
  const int*   ei    = (const int*)d_in[1];
  const int*   etype = (const int*)d_in[2];
  const int*   batch = (const int*)d_in[3];
  const float* W1    = (const float*)d_in[4];
  const float* root1 = (const float*)d_in[5];
  const float* b1    = (const float*)d_in[6];
  const float* W2    = (const float*)d_in[7];
  const float* root2 = (const float*)d_in[8];
  const float* b2    = (const float*)d_in[9];

  const int N = in_sizes[0] / 64;
  const int E = in_sizes[1] / 2;
  const int R = in_sizes[4] / (64 * 64);
  const int G = out_size / 64;
  const int* srcp = ei;
  const int* dstp = ei + E;

  // workspace carve-up (256B aligned): inv | acc | h | Y | gsum+gcnt  (~157 MB)
  char* ws = (char*)d_ws;
  size_t off = 0;
  auto carve = [&](size_t bytes) -> void* {
    void* p = ws + off; off = (off + bytes + 255) & ~(size_t)255; return p;
  };
  float*          inv  = (float*)carve((size_t)N * R * 4);
  float*          acc  = (float*)carve((size_t)N * 64 * 4);
  float*          h    = (float*)carve((size_t)N * 64 * 4);
  unsigned short* Y    = (unsigned short*)carve((size_t)N * R * 64 * 2);
  float*          gsum = (float*)carve(((size_t)G * 64 + G) * 4);
  float*          gcnt = gsum + (size_t)G * 64;
  (void)ws_size; (void)n_in;

  const int nInv = N * R;
  zero_f32<<<(nInv + 255) / 256, 256, 0, stream>>>(inv, nInv);
  zero_f32<<<(G * 64 + 255) / 256, 256, 0, stream>>>(gsum, G * 64);

  count_edges<<<(E + 255) / 256, 256, 0, stream>>>(dstp, etype, inv, E, R);
  invert_cnt<<<(nInv + 255) / 256, 256, 0, stream>>>(inv, nInv);

  dim3 tgrid(128, R + 1);
  const int nh = N * 64;
  const int eBlocks = 8192;

  // ---- layer 1 ----
  transform<<<tgrid, 256, 0, stream>>>(x, W1, root1, b1, Y, acc, N, R);
  edge_agg<<<eBlocks, 256, 0, stream>>>(Y, srcp, dstp, etype, inv, acc, E, R);
  relu_f32<<<(nh + 255) / 256, 256, 0, stream>>>(acc, h, nh);

  // ---- layer 2 ----
  transform<<<tgrid, 256, 0, stream>>>(h, W2, root2, b2, Y, acc, N, R);
  edge_agg<<<eBlocks, 256, 0, stream>>>(Y, srcp, dstp, etype, inv, acc, E, R);

  // ---- global mean pool ----
  pool_sum<<<(nh + 255) / 256, 256, 0, stream>>>(acc, batch, gsum, nh);
  gcnt_bounds<<<1, 128, 0, stream>>>(batch, gcnt, N, G);
  finalize<<<(G * 64 + 255) / 256, 256, 0, stream>>>(gsum, gcnt, (float*)d_out, G);
}

// Round 5
// 719.532 us; speedup vs baseline: 2.4344x; 1.5805x over previous
//
#include <hip/hip_runtime.h>
#include <stdint.h>

// ---------- types ----------
typedef __attribute__((ext_vector_type(8))) short short8;
typedef __attribute__((ext_vector_type(4))) float floatx4;

__device__ inline float bf2f(unsigned short u) {
  union { unsigned int i; float f; } v; v.i = ((unsigned int)u) << 16; return v.f;
}
__device__ inline unsigned short f2bf(float f) {
  union { float f; unsigned int i; } v; v.f = f;
  unsigned int r = v.i + 0x7FFFu + ((v.i >> 16) & 1u);  // round-nearest-even
  return (unsigned short)(r >> 16);
}

// ---------- utility ----------
__global__ void zero_f32(float* __restrict__ p, int n) {
  int i = blockIdx.x * blockDim.x + threadIdx.x;
  if (i < n) p[i] = 0.0f;
}
__global__ void zero_i32(int* __restrict__ p, int n) {
  int i = blockIdx.x * blockDim.x + threadIdx.x;
  if (i < n) p[i] = 0;
}

// counts: ecnt[d]++ (int, CSR build) and inv[d*R+et]+=1 (float, mean weights)
__global__ void count_both(const int* __restrict__ dst, const int* __restrict__ et,
                           int* __restrict__ ecnt, float* __restrict__ inv, int E, int R) {
  int e = blockIdx.x * blockDim.x + threadIdx.x;
  if (e < E) {
    int d = dst[e];
    atomicAdd(&ecnt[d], 1);
    atomicAdd(&inv[(size_t)d * R + et[e]], 1.0f);
  }
}

__global__ void invert_cnt(float* __restrict__ p, int n) {
  int i = blockIdx.x * blockDim.x + threadIdx.x;
  if (i < n) p[i] = 1.0f / fmaxf(p[i], 1.0f);
}

// ---------- exclusive scan of ecnt[N] -> eptr[N] (+eptr[N]=E), epos copy ----------
#define SCAN_T 256
#define SCAN_E 4   // 1024 elems per block

__global__ void scan1(const int* __restrict__ cnt, int* __restrict__ bsum, int n) {
  __shared__ int lds[SCAN_T];
  int base = blockIdx.x * (SCAN_T * SCAN_E);
  int tid = threadIdx.x;
  int s = 0;
#pragma unroll
  for (int j = 0; j < SCAN_E; ++j) {
    int i = base + tid * SCAN_E + j;
    if (i < n) s += cnt[i];
  }
  lds[tid] = s; __syncthreads();
  for (int off = SCAN_T / 2; off > 0; off >>= 1) {
    if (tid < off) lds[tid] += lds[tid + off];
    __syncthreads();
  }
  if (tid == 0) bsum[blockIdx.x] = lds[0];
}

__global__ void scan2(int* __restrict__ bsum, int* __restrict__ eptr, int nb, int n) {
  if (threadIdx.x == 0 && blockIdx.x == 0) {
    int run = 0;
    for (int b = 0; b < nb; ++b) { int v = bsum[b]; bsum[b] = run; run += v; }
    eptr[n] = run;   // total edge count
  }
}

__global__ void scan3(const int* __restrict__ cnt, const int* __restrict__ bsum,
                      int* __restrict__ eptr, int* __restrict__ epos, int n) {
  __shared__ int lds[SCAN_T];
  int base = blockIdx.x * (SCAN_T * SCAN_E);
  int tid = threadIdx.x;
  int loc[SCAN_E]; int s = 0;
#pragma unroll
  for (int j = 0; j < SCAN_E; ++j) {
    int i = base + tid * SCAN_E + j;
    loc[j] = (i < n) ? cnt[i] : 0; s += loc[j];
  }
  lds[tid] = s; __syncthreads();
  for (int off = 1; off < SCAN_T; off <<= 1) {   // Hillis-Steele inclusive
    int v = (tid >= off) ? lds[tid - off] : 0;
    __syncthreads();
    lds[tid] += v;
    __syncthreads();
  }
  int run = (tid > 0 ? lds[tid - 1] : 0) + bsum[blockIdx.x];
#pragma unroll
  for (int j = 0; j < SCAN_E; ++j) {
    int i = base + tid * SCAN_E + j;
    if (i < n) { eptr[i] = run; epos[i] = run; run += loc[j]; }
  }
}

// scatter edges into dst-sorted order; entry = (src<<3)|rel  (src<2^17, R=8)
__global__ void scatter_edges(const int* __restrict__ src, const int* __restrict__ dst,
                              const int* __restrict__ et, int* __restrict__ epos,
                              unsigned* __restrict__ entry, int E) {
  int e = blockIdx.x * blockDim.x + threadIdx.x;
  if (e < E) {
    int p = atomicAdd(&epos[dst[e]], 1);
    entry[p] = ((unsigned)src[e] << 3) | (unsigned)et[e];
  }
}

// ---------- transform: Y[n][g*64+c] = sum_d act(X[n][d]) * W_g[d][c]  (g<R, bf16 out)
// ----------            acc[n][c]    = b[c] + sum_d act(X[n][d]) * root[d][c] (g==R)
// act = relu if relu_in (layer 2 reads layer-1 acc directly; fused relu).
// MFMA 16x16x32 bf16; A/B/C layouts per m89/m91.
__global__ void __launch_bounds__(256)
transform(const float* __restrict__ X, const float* __restrict__ W,
          const float* __restrict__ root, const float* __restrict__ bias,
          unsigned short* __restrict__ Y, float* __restrict__ acc, int N, int R,
          int relu_in)
{
  const int g    = blockIdx.y;            // 0..R  (R == root/bias group)
  const int lane = threadIdx.x & 63;
  const int wave = threadIdx.x >> 6;
  const int lc   = lane & 15;
  const int quad = lane >> 4;
  const float* B = (g < R) ? (W + (size_t)g * 64 * 64) : root;

  short8 bfrag[2][4];
#pragma unroll
  for (int kc = 0; kc < 2; ++kc)
#pragma unroll
    for (int nt = 0; nt < 4; ++nt) {
      short8 f;
#pragma unroll
      for (int j = 0; j < 8; ++j)
        f[j] = (short)f2bf(B[(size_t)(kc * 32 + quad * 8 + j) * 64 + nt * 16 + lc]);
      bfrag[kc][nt] = f;
    }

  const int tiles  = (N + 15) >> 4;
  const int stride = gridDim.x * 4;
  for (int t = blockIdx.x * 4 + wave; t < tiles; t += stride) {
    const int nb  = t << 4;
    const int row = min(nb + lc, N - 1);
    const float* xr = X + (size_t)row * 64;
    short8 a0, a1;
#pragma unroll
    for (int j = 0; j < 8; ++j) {
      float v0 = xr[quad * 8 + j];
      float v1 = xr[32 + quad * 8 + j];
      if (relu_in) { v0 = fmaxf(v0, 0.f); v1 = fmaxf(v1, 0.f); }
      a0[j] = (short)f2bf(v0);
      a1[j] = (short)f2bf(v1);
    }
#pragma unroll
    for (int nt = 0; nt < 4; ++nt) {
      floatx4 d = {0.f, 0.f, 0.f, 0.f};
      d = __builtin_amdgcn_mfma_f32_16x16x32_bf16(a0, bfrag[0][nt], d, 0, 0, 0);
      d = __builtin_amdgcn_mfma_f32_16x16x32_bf16(a1, bfrag[1][nt], d, 0, 0, 0);
      const int c = nt * 16 + lc;
      if (g < R) {
#pragma unroll
        for (int i = 0; i < 4; ++i) {
          int r_ = nb + quad * 4 + i;
          if (r_ < N) Y[(size_t)r_ * (R * 64) + g * 64 + c] = f2bf(d[i]);
        }
      } else {
        float bv = bias[c];
#pragma unroll
        for (int i = 0; i < 4; ++i) {
          int r_ = nb + quad * 4 + i;
          if (r_ < N) acc[(size_t)r_ * 64 + c] = d[i] + bv;
        }
      }
    }
  }
}

// ---------- CSR edge aggregation: one wave owns one dst node. No atomics.
// acc[d][lane] += sum_{e in seg(d)} Y[src_e][rel_e*64+lane] * inv[d*8+rel_e]
__global__ void __launch_bounds__(256)
edge_agg_csr(const unsigned short* __restrict__ Y, const int* __restrict__ eptr,
             const unsigned* __restrict__ entry, const float* __restrict__ inv,
             float* __restrict__ acc, int N)
{
  const int wid  = (blockIdx.x * blockDim.x + threadIdx.x) >> 6;
  const int lane = threadIdx.x & 63;
  if (wid >= N) return;
  const int lo = eptr[wid], hi = eptr[wid + 1];
  const float invv = inv[(size_t)wid * 8 + (lane & 7)];   // lanes 0..7 hold the 8 rel weights
  float sum = 0.f;
  int e = lo;
  for (; e + 4 <= hi; e += 4) {
    unsigned en0 = entry[e], en1 = entry[e + 1], en2 = entry[e + 2], en3 = entry[e + 3];
    float v0 = bf2f(Y[(size_t)(en0 >> 3) * 512 + (en0 & 7) * 64 + lane]);
    float v1 = bf2f(Y[(size_t)(en1 >> 3) * 512 + (en1 & 7) * 64 + lane]);
    float v2 = bf2f(Y[(size_t)(en2 >> 3) * 512 + (en2 & 7) * 64 + lane]);
    float v3 = bf2f(Y[(size_t)(en3 >> 3) * 512 + (en3 & 7) * 64 + lane]);
    sum += v0 * __shfl(invv, (int)(en0 & 7)) + v1 * __shfl(invv, (int)(en1 & 7))
         + v2 * __shfl(invv, (int)(en2 & 7)) + v3 * __shfl(invv, (int)(en3 & 7));
  }
  for (; e < hi; ++e) {
    unsigned en = entry[e];
    float v = bf2f(Y[(size_t)(en >> 3) * 512 + (en & 7) * 64 + lane]);
    sum += v * __shfl(invv, (int)(en & 7));
  }
  acc[(size_t)wid * 64 + lane] += sum;
}

// graph segment boundaries from sorted batch: glo[g] = lower_bound(batch, g); glo[G]=N
__global__ void glo_bounds(const int* __restrict__ batch, int* __restrict__ glo,
                           int N, int G) {
  int g = blockIdx.x * blockDim.x + threadIdx.x;
  if (g > G) return;
  if (g == G) { glo[G] = N; return; }
  int lo = 0, hi = N;
  while (lo < hi) { int mid = (lo + hi) >> 1; if (batch[mid] < g) lo = mid + 1; else hi = mid; }
  glo[g] = lo;
}

// fused mean-pool + finalize: one block per graph, contiguous node segment
__global__ void __launch_bounds__(256)
pool(const float* __restrict__ acc, const int* __restrict__ glo,
     float* __restrict__ out, int G)
{
  const int g = blockIdx.x;
  const int lane = threadIdx.x & 63;
  const int w = threadIdx.x >> 6;
  const int lo = glo[g], hi = glo[g + 1];
  float s = 0.f;
  for (int n = lo + w; n < hi; n += 4) s += acc[(size_t)n * 64 + lane];
  __shared__ float red[4][64];
  red[w][lane] = s;
  __syncthreads();
  if (w == 0) {
    float t = red[0][lane] + red[1][lane] + red[2][lane] + red[3][lane];
    out[(size_t)g * 64 + lane] = t / fmaxf((float)(hi - lo), 1.0f);
  }
}

// ---------- launch ----------
extern "C" void kernel_launch(void* const* d_in, const int* in_sizes, int n_in,
                              void* d_out, int out_size, void* d_ws, size_t ws_size,
                              hipStream_t stream)
{
  const float* x     = (const float*)d_in[0];
  const int*   ei    = (const int*)d_in[1];
  const int*   etype = (const int*)d_in[2];
  const int*   batch = (const int*)d_in[3];
  const float* W1    = (const float*)d_in[4];
  const float* root1 = (const float*)d_in[5];
  const float* b1    = (const float*)d_in[6];
  const float* W2    = (const float*)d_in[7];
  const float* root2 = (const float*)d_in[8];
  const float* b2    = (const float*)d_in[9];

  const int N = in_sizes[0] / 64;
  const int E = in_sizes[1] / 2;
  const int R = in_sizes[4] / (64 * 64);
  const int G = out_size / 64;
  const int* srcp = ei;
  const int* dstp = ei + E;

  // workspace carve-up (256B aligned), ~165 MB total
  char* ws = (char*)d_ws;
  size_t off = 0;
  auto carve = [&](size_t bytes) -> void* {
    void* p = ws + off; off = (off + bytes + 255) & ~(size_t)255; return p;
  };
  float*          inv   = (float*)carve((size_t)N * R * 4);
  float*          accA  = (float*)carve((size_t)N * 64 * 4);
  float*          accB  = (float*)carve((size_t)N * 64 * 4);
  unsigned short* Y     = (unsigned short*)carve((size_t)N * R * 64 * 2);
  int*            ecnt  = (int*)carve((size_t)N * 4);
  int*            eptr  = (int*)carve((size_t)(N + 1) * 4);
  int*            epos  = (int*)carve((size_t)N * 4);
  unsigned*       entry = (unsigned*)carve((size_t)E * 4);
  int*            bsum  = (int*)carve(1024 * 4);
  int*            glo   = (int*)carve((size_t)(G + 1) * 4);
  (void)ws_size; (void)n_in;

  const int nInv = N * R;
  const int nb_scan = (N + SCAN_T * SCAN_E - 1) / (SCAN_T * SCAN_E);

  // ---- CSR build + mean weights ----
  zero_f32<<<(nInv + 255) / 256, 256, 0, stream>>>(inv, nInv);
  zero_i32<<<(N + 255) / 256, 256, 0, stream>>>(ecnt, N);
  count_both<<<(E + 255) / 256, 256, 0, stream>>>(dstp, etype, ecnt, inv, E, R);
  invert_cnt<<<(nInv + 255) / 256, 256, 0, stream>>>(inv, nInv);
  scan1<<<nb_scan, SCAN_T, 0, stream>>>(ecnt, bsum, N);
  scan2<<<1, 64, 0, stream>>>(bsum, eptr, nb_scan, N);
  scan3<<<nb_scan, SCAN_T, 0, stream>>>(ecnt, bsum, eptr, epos, N);
  scatter_edges<<<(E + 255) / 256, 256, 0, stream>>>(srcp, dstp, etype, epos, entry, E);

  dim3 tgrid(128, R + 1);
  const int aggBlocks = (N * 64 + 255) / 256;

  // ---- layer 1 ----
  transform<<<tgrid, 256, 0, stream>>>(x, W1, root1, b1, Y, accA, N, R, 0);
  edge_agg_csr<<<aggBlocks, 256, 0, stream>>>(Y, eptr, entry, inv, accA, N);

  // ---- layer 2 (relu fused into transform's input read) ----
  transform<<<tgrid, 256, 0, stream>>>(accA, W2, root2, b2, Y, accB, N, R, 1);
  edge_agg_csr<<<aggBlocks, 256, 0, stream>>>(Y, eptr, entry, inv, accB, N);

  // ---- global mean pool (fused finalize) ----
  glo_bounds<<<1, 128, 0, stream>>>(batch, glo, N, G);
  pool<<<G, 256, 0, stream>>>(accB, glo, (float*)d_out, G);
}